// Round 19
// baseline (273.676 us; speedup 1.0000x reference)
//
#include <hip/hip_runtime.h>
#include <cstdint>
#include <cstddef>

// GRU B=16384 T=64 H=32, 3 bidir layers + FC(64->2) + tanh.
// R18: R17 with the ext_vector_type init-list compile error fixed (mk2 helper).
// (a) gate arithmetic on f32x2 vectors -> v_pk_*_f32 packed codegen (IEEE-
//     identical fp32 math), (b) odd waves s_sleep once pre-loop to desync the
//     two resident waves' gate-VALU vs MFMA phases.
// Base: R16 direction-split (2,T,B,32) f16 buffers (no store-RFO), f16
// weights/h/activations, fp32 acc, 16 seqs/wave, permuted gate rows, zero-LDS
// recurrence, exp2-folded weights, shared rcp, delayed h-stores, FC fused in L2.

#define BB 16384
#define TT 64
#define PS ((size_t)BB * 32)        // shorts per t-plane per direction
#define DS ((size_t)TT * PS)        // shorts per direction buffer
#define PT ((size_t)TT * BB * 2)    // floats per direction-partial buffer

typedef __attribute__((ext_vector_type(8))) _Float16 f16x8;
typedef __attribute__((ext_vector_type(4))) float f32x4;
typedef __attribute__((ext_vector_type(2))) float f32x2;

#if __has_builtin(__builtin_amdgcn_exp2f)
#define EXP2(x) __builtin_amdgcn_exp2f(x)
#else
#define EXP2(x) exp2f(x)
#endif
#if __has_builtin(__builtin_amdgcn_rcpf)
#define RCP(x) __builtin_amdgcn_rcpf(x)
#else
#define RCP(x) (1.0f / (x))
#endif

#define SR (-1.4426950408889634f)   // -log2(e)   for r,z gates
#define SN (-2.8853900817779268f)   // -2*log2(e) for n gate

__device__ __forceinline__ f32x2 mk2(float a, float b) {
    f32x2 v; v.x = a; v.y = b; return v;
}
__device__ __forceinline__ float tanh_fast(float x) { return 2.0f / (1.0f + __expf(-2.0f * x)) - 1.0f; }
__device__ __forceinline__ unsigned short f2h(float f) {
    _Float16 h = (_Float16)f;                      // RNE
    return __builtin_bit_cast(unsigned short, h);
}
__device__ __forceinline__ unsigned int cvt_pkh(float a, float b) {
#if __has_builtin(__builtin_amdgcn_cvt_pkrtz)
    typedef __fp16 h2_t __attribute__((ext_vector_type(2)));
    h2_t p = __builtin_amdgcn_cvt_pkrtz(a, b);
    return __builtin_bit_cast(unsigned int, p);
#else
    return (unsigned int)f2h(a) | ((unsigned int)f2h(b) << 16);
#endif
}
__device__ __forceinline__ f32x4 mfma16h(f16x8 a, f16x8 b, f32x4 c) {
    return __builtin_amdgcn_mfma_f32_16x16x32_f16(a, b, c, 0, 0, 0);
}

// Gates for a q-pair on packed f32 vectors (v_pk_* codegen).
// Inputs are exp2-prescaled preactivations (bias carried in MFMA C operand).
// sigma(x) = rcp(1+exp2(SR*x)); tanh(v) = 2*rcp(1+exp2(SN*v)) - 1.
__device__ __forceinline__ void gate_pair2(f32x2 aR, f32x2 aZ, f32x2 xN, f32x2 hN,
                                           f32x2& hp) {
    f32x2 er = mk2(EXP2(aR.x), EXP2(aR.y));
    f32x2 ez = mk2(EXP2(aZ.x), EXP2(aZ.y));
    f32x2 Ar = er + 1.f;
    f32x2 Az = ez + 1.f;
    float iR = RCP(Ar.x * Ar.y);
    float iZ = RCP(Az.x * Az.y);
    f32x2 r = mk2(iR * Ar.y, iR * Ar.x);
    f32x2 z = mk2(iZ * Az.y, iZ * Az.x);
    f32x2 v = r * hN + xN;                         // pk_fma
    f32x2 en = mk2(EXP2(v.x), EXP2(v.y));
    f32x2 An = en + 1.f;
    float iN = RCP(An.x * An.y);
    f32x2 n = mk2(fmaf(2.f, iN * An.y, -1.f), fmaf(2.f, iN * An.x, -1.f));
    hp = z * (hp - n) + n;                         // pk_sub / pk_fma
}

// A: lane = A[m=lane&15][k=(lane>>4)*8+j]   B: lane = B[k=(lane>>4)*8+j][n=lane&15]
// D: lane = D[row=(lane>>4)*4+reg][col=lane&15]
// Gate-row permutation: block row position (T*16 + qd*4 + q) <- original unit 8qd+4T+q.

template<bool IS_L0, bool IS_LAST>
__global__ __launch_bounds__(256, 2)
void gru_mfma(const float* __restrict__ x0,
              const unsigned short* __restrict__ bin,      // f16 bits (2,T,B,32)
              const float* __restrict__ Wih,               // (2,96,I)
              const float* __restrict__ Whh,               // (2,96,32)
              const float* __restrict__ bih,               // (2,96)
              const float* __restrict__ bhh,               // (2,96)
              unsigned short* __restrict__ bout,           // f16 bits (2,T,B,32)
              const float* __restrict__ Wfc,               // (2,64)  [LAST]
              float* __restrict__ pbase)                   // (2,T,B,2) fp32 [LAST]
{
    const int tid  = threadIdx.x;
    const int lane = tid & 63;
    const int wv   = tid >> 6;
    const int g    = blockIdx.x * 4 + wv;        // 0..2047
    const int d    = g >> 10;
    const int b0   = (g & 1023) * 16;            // 16 seqs per wave
    const int col  = lane & 15;
    const int qd   = lane >> 4;

    // ---- Whh A-frags (single f16), permuted rows, exp2-prescaled ----
    f16x8 whhF[6];
    {
        const float* wsrc = Whh + d * 96 * 32;
        #pragma unroll
        for (int t = 0; t < 6; ++t) {
            const float sc = (t < 4) ? SR : SN;
            const int row = (t >> 1) * 32 + 8 * (col >> 2) + 4 * (t & 1) + (col & 3);
            const float* pr = wsrc + row * 32 + qd * 8;
            unsigned short wbits[8];
            #pragma unroll
            for (int j = 0; j < 8; ++j) wbits[j] = f2h(pr[j] * sc);
            whhF[t] = __builtin_bit_cast(f16x8, *(uint4*)wbits);
        }
    }

    // ---- Wih A-frags (single f16, permuted, prescaled) or L0 scalar weights ----
    f16x8 wihF[6][2];
    float w0c[6][4], w1c[6][4];
    if constexpr (!IS_L0) {
        const float* wsrc = Wih + d * 96 * 64;
        #pragma unroll
        for (int t = 0; t < 6; ++t) {
            const float sc = (t < 4) ? SR : SN;
            const int row = (t >> 1) * 32 + 8 * (col >> 2) + 4 * (t & 1) + (col & 3);
            #pragma unroll
            for (int kc = 0; kc < 2; ++kc) {
                const float* pr = wsrc + row * 64 + kc * 32 + qd * 8;
                unsigned short wbits[8];
                #pragma unroll
                for (int j = 0; j < 8; ++j) wbits[j] = f2h(pr[j] * sc);
                wihF[t][kc] = __builtin_bit_cast(f16x8, *(uint4*)wbits);
            }
        }
    } else {
        #pragma unroll
        for (int t = 0; t < 6; ++t) {
            const float sc = (t < 4) ? SR : SN;
            #pragma unroll
            for (int q = 0; q < 4; ++q) {
                const int row = (t >> 1) * 32 + 8 * qd + 4 * (t & 1) + q;
                const float* pr = Wih + d * 96 * 2 + row * 2;
                w0c[t][q] = pr[0] * sc;
                w1c[t][q] = pr[1] * sc;
            }
        }
    }

    // ---- biases as C-operand frags (prescaled) ----
    f32x4 biasIn[6], biasHN[2];
    {
        const float* bi = bih + d * 96;
        const float* bh = bhh + d * 96;
        #pragma unroll
        for (int t = 0; t < 4; ++t) {
            const int off = (t >> 1) * 32 + 8 * qd + 4 * (t & 1);
            float4 a = *(const float4*)(bi + off);
            float4 b = *(const float4*)(bh + off);
            biasIn[t][0] = (a.x + b.x) * SR; biasIn[t][1] = (a.y + b.y) * SR;
            biasIn[t][2] = (a.z + b.z) * SR; biasIn[t][3] = (a.w + b.w) * SR;
        }
        #pragma unroll
        for (int T = 0; T < 2; ++T) {
            const int off = 64 + 8 * qd + 4 * T;
            float4 a = *(const float4*)(bi + off);
            float4 b = *(const float4*)(bh + off);
            biasIn[4 + T][0] = a.x * SN; biasIn[4 + T][1] = a.y * SN;
            biasIn[4 + T][2] = a.z * SN; biasIn[4 + T][3] = a.w * SN;
            biasHN[T][0] = b.x * SN; biasHN[T][1] = b.y * SN;
            biasHN[T][2] = b.z * SN; biasHN[T][3] = b.w * SN;
        }
    }

    // ---- FC weights per lane (LAST): unit u = 8*qd + 4*T + q ----
    float wf0[2][4], wf1[2][4];
    if constexpr (IS_LAST) {
        #pragma unroll
        for (int T = 0; T < 2; ++T)
            #pragma unroll
            for (int q = 0; q < 4; ++q) {
                const int u = 8 * qd + 4 * T + q;
                wf0[T][q] = Wfc[d * 32 + u];
                wf1[T][q] = Wfc[64 + d * 32 + u];
            }
    }

    const int t0 = d ? (TT - 1) : 0;
    const int dt = d ? -1 : 1;
    const ptrdiff_t dplane = (ptrdiff_t)dt * (ptrdiff_t)PS;   // one t-plane step

    f16x8 hF = {};
    float hprev[2][4] = {{0.f,0.f,0.f,0.f},{0.f,0.f,0.f,0.f}};

    auto REC = [&](f32x4 (&acc)[6], f32x4 (&accHN)[2]) {
        #pragma unroll
        for (int t = 0; t < 4; ++t)
            acc[t] = mfma16h(whhF[t], hF, acc[t]);
        #pragma unroll
        for (int T = 0; T < 2; ++T)
            accHN[T] = mfma16h(whhF[4 + T], hF, biasHN[T]);
    };

    auto PROJ = [&](f32x4 (&accN)[6], uint4 nx0, uint4 nx1, float2 nxs) {
        if constexpr (!IS_L0) {
            f16x8 a0 = __builtin_bit_cast(f16x8, nx0);   // k 0..31  = fwd units
            f16x8 a1 = __builtin_bit_cast(f16x8, nx1);   // k 32..63 = bwd units
            #pragma unroll
            for (int t = 0; t < 6; ++t) {
                accN[t] = mfma16h(wihF[t][0], a0, biasIn[t]);
                accN[t] = mfma16h(wihF[t][1], a1, accN[t]);
            }
        } else {
            #pragma unroll
            for (int t = 0; t < 6; ++t)
                #pragma unroll
                for (int q = 0; q < 4; ++q)
                    accN[t][q] = fmaf(nxs.x, w0c[t][q], fmaf(nxs.y, w1c[t][q], biasIn[t][q]));
        }
    };

    // ---- gates (packed f32 math); delayed h-store (L0/L1) or FC partial (LAST) ----
    auto GATES = [&](f32x4 (&acc)[6], f32x4 (&accHN)[2], unsigned short* outp,
                     uint4& hwP, unsigned short*& opP, float* poutp) {
        unsigned int hw[4];
        #pragma unroll
        for (int T = 0; T < 2; ++T) {
            f32x2 hp01 = mk2(hprev[T][0], hprev[T][1]);
            f32x2 hp23 = mk2(hprev[T][2], hprev[T][3]);
            gate_pair2(mk2(acc[T][0], acc[T][1]), mk2(acc[2 + T][0], acc[2 + T][1]),
                       mk2(acc[4 + T][0], acc[4 + T][1]), mk2(accHN[T][0], accHN[T][1]), hp01);
            gate_pair2(mk2(acc[T][2], acc[T][3]), mk2(acc[2 + T][2], acc[2 + T][3]),
                       mk2(acc[4 + T][2], acc[4 + T][3]), mk2(accHN[T][2], accHN[T][3]), hp23);
            hprev[T][0] = hp01.x; hprev[T][1] = hp01.y;
            hprev[T][2] = hp23.x; hprev[T][3] = hp23.y;
            hw[2 * T]     = cvt_pkh(hp01.x, hp01.y);
            hw[2 * T + 1] = cvt_pkh(hp23.x, hp23.y);
        }
        hF = __builtin_bit_cast(f16x8, *(uint4*)hw);
        if constexpr (IS_LAST) {
            float p0 = 0.f, p1 = 0.f;
            #pragma unroll
            for (int T = 0; T < 2; ++T)
                #pragma unroll
                for (int q = 0; q < 4; ++q) {
                    p0 = fmaf(hprev[T][q], wf0[T][q], p0);
                    p1 = fmaf(hprev[T][q], wf1[T][q], p1);
                }
            p0 += __shfl_xor(p0, 16); p0 += __shfl_xor(p0, 32);
            p1 += __shfl_xor(p1, 16); p1 += __shfl_xor(p1, 32);
            if (qd == 0) *(float2*)poutp = make_float2(p0, p1);
        } else {
            *(uint4*)opP = hwP;                 // store the 2-steps-old value
            hwP = *(uint4*)hw;                  // bank this step's value
            opP = outp;
        }
    };

    // ---- x streams: even loads x[2k+2], odd loads x[2k+3]; F/B buffer pair ----
    f32x4 accA[6], accB[6], accHN[2];
    uint4 xc0 = {}, xc1 = {}, xe0 = {}, xe1 = {};
    float2 xsc = {}, xse = {};
    const unsigned short* xFE = nullptr; const unsigned short* xBE = nullptr;
    const unsigned short* xFO = nullptr; const unsigned short* xBO = nullptr;
    const float* xfpE = nullptr; const float* xfpO = nullptr;

    if constexpr (!IS_L0) {
        const unsigned short* pF = bin + (size_t)t0 * PS + (size_t)(b0 + col) * 32 + qd * 8;
        const unsigned short* pB = pF + DS;
        uint4 a = *(const uint4*)pF, b = *(const uint4*)pB;
        PROJ(accA, a, b, {});                         // acc for step 0
        xc0 = *(const uint4*)(pF + dplane);           // x[1]
        xc1 = *(const uint4*)(pB + dplane);
        xFE = pF + 2 * dplane; xBE = pB + 2 * dplane; // x[2]
        xFO = pF + 3 * dplane; xBO = pB + 3 * dplane; // x[3]
    } else {
        const float* p0 = x0 + ((size_t)(b0 + col) * TT + t0) * 2;
        float2 xs0 = *(const float2*)p0;
        PROJ(accA, {}, {}, xs0);
        xsc = *(const float2*)(p0 + dt * 2);          // x[1]
        xfpE = p0 + dt * 4;                           // x[2]
        xfpO = p0 + dt * 6;                           // x[3]
    }

    unsigned short* optrA = nullptr; unsigned short* optrB = nullptr;
    float* poutA = nullptr; float* poutB = nullptr;
    const ptrdiff_t dpp = (ptrdiff_t)dt * (ptrdiff_t)BB * 2;
    if constexpr (IS_LAST) {
        poutA = pbase + (size_t)d * PT + ((size_t)t0 * BB + b0 + col) * 2;
        poutB = poutA + dpp;
    } else {
        optrA = bout + (size_t)d * DS + (size_t)t0 * PS + (size_t)(b0 + col) * 32 + qd * 8;
        optrB = optrA + dplane;
    }

    // phase-skew: odd waves sleep once so their gate phase overlays the
    // even waves' MFMA phase instead of colliding on the same pipe
#if __has_builtin(__builtin_amdgcn_s_sleep)
    if (wv & 1) __builtin_amdgcn_s_sleep(8);
#endif

    // delayed-store state (L0/L1): primed with zero-writes to step-0/1 addresses
    uint4 hwPrevA = {}, hwPrevB = {};
    unsigned short* opPrevA = optrA;
    unsigned short* opPrevB = optrB;

    for (int k = 0; k < 31; ++k) {                    // steps 0..61
        if constexpr (!IS_L0) {
            xe0 = *(const uint4*)xFE; xe1 = *(const uint4*)xBE;
            xFE += 2 * dplane; xBE += 2 * dplane;
        } else { xse = *(const float2*)xfpE; xfpE += dt * 4; }
        REC(accA, accHN);
        PROJ(accB, xc0, xc1, xsc);
        GATES(accA, accHN, optrA, hwPrevA, opPrevA, poutA);
        if constexpr (IS_LAST) poutA += 2 * dpp; else optrA += 2 * dplane;
        if constexpr (!IS_L0) {
            xc0 = *(const uint4*)xFO; xc1 = *(const uint4*)xBO;
            xFO += 2 * dplane; xBO += 2 * dplane;
        } else { xsc = *(const float2*)xfpO; xfpO += dt * 4; }
        REC(accB, accHN);
        PROJ(accA, xe0, xe1, xse);
        GATES(accB, accHN, optrB, hwPrevB, opPrevB, poutB);
        if constexpr (IS_LAST) poutB += 2 * dpp; else optrB += 2 * dplane;
    }
    REC(accA, accHN);                                 // step 62
    PROJ(accB, xc0, xc1, xsc);
    GATES(accA, accHN, optrA, hwPrevA, opPrevA, poutA);
    REC(accB, accHN);                                 // step 63
    GATES(accB, accHN, optrB, hwPrevB, opPrevB, poutB);
    if constexpr (!IS_LAST) {
        *(uint4*)opPrevA = hwPrevA;                   // flush banked values
        *(uint4*)opPrevB = hwPrevB;
    }
}

// out[b][t] = tanh(pf[t][b] + pb[t][b] + bfc), with an LDS 64x64 transpose
__global__ __launch_bounds__(256)
void fc_finish(const float* __restrict__ pf,    // (T,B,2)
               const float* __restrict__ pb,    // (T,B,2)
               const float* __restrict__ bfc,   // (2,)
               float* __restrict__ out)         // (B,T,2)
{
    __shared__ float2 tile[64][65];
    const int tid = threadIdx.x;
    const int bbase = blockIdx.x * 64;
    const float c0 = bfc[0], c1 = bfc[1];
    #pragma unroll
    for (int tp = 0; tp < 16; ++tp) {             // read coalesced over b
        const int t = tp * 4 + (tid >> 6);
        const int bl = tid & 63;
        const size_t idx = ((size_t)t * BB + bbase + bl) * 2;
        float2 vf = *(const float2*)(pf + idx);
        float2 vb = *(const float2*)(pb + idx);
        float2 o;
        o.x = tanh_fast(vf.x + vb.x + c0);
        o.y = tanh_fast(vf.y + vb.y + c1);
        tile[t][bl] = o;
    }
    __syncthreads();
    #pragma unroll
    for (int bp = 0; bp < 16; ++bp) {             // write coalesced over t
        const int bl = bp * 4 + (tid >> 6);
        const int t = tid & 63;
        *(float2*)(out + ((size_t)(bbase + bl) * TT + t) * 2) = tile[t][bl];
    }
}

extern "C" void kernel_launch(void* const* d_in, const int* in_sizes, int n_in,
                              void* d_out, int out_size, void* d_ws, size_t ws_size,
                              hipStream_t stream)
{
    const float* x    = (const float*)d_in[0];
    const float* Wih0 = (const float*)d_in[1];
    const float* Whh0 = (const float*)d_in[2];
    const float* bih0 = (const float*)d_in[3];
    const float* bhh0 = (const float*)d_in[4];
    const float* WihL = (const float*)d_in[5];
    const float* WhhL = (const float*)d_in[6];
    const float* bihL = (const float*)d_in[7];
    const float* bhhL = (const float*)d_in[8];
    const float* Wfc  = (const float*)d_in[9];
    const float* bfc  = (const float*)d_in[10];

    unsigned short* buf0 = (unsigned short*)d_ws;           // (2,T,B,32) f16
    unsigned short* buf1 = buf0 + 2 * DS;                   // (2,T,B,32) f16
    float* pbase = (float*)d_ws;                            // (2,T,B,2) fp32, reuses buf0
    float* out = (float*)d_out;

    gru_mfma<true, false><<<512, 256, 0, stream>>>(
        x, nullptr, Wih0, Whh0, bih0, bhh0, buf0, nullptr, nullptr);
    gru_mfma<false, false><<<512, 256, 0, stream>>>(
        nullptr, buf0, WihL, WhhL, bihL, bhhL, buf1, nullptr, nullptr);
    gru_mfma<false, true><<<512, 256, 0, stream>>>(
        nullptr, buf1, WihL + 2 * 96 * 64, WhhL + 2 * 96 * 32,
        bihL + 2 * 96, bhhL + 2 * 96, nullptr, Wfc, pbase);
    fc_finish<<<BB / 64, 256, 0, stream>>>(
        pbase, pbase + PT, bfc, out);
}

// Round 20
// 267.021 us; speedup vs baseline: 1.0249x; 1.0249x over previous
//
#include <hip/hip_runtime.h>
#include <cstdint>
#include <cstddef>

// GRU B=16384 T=64 H=32, 3 bidir layers + FC(64->2) + tanh.
// R19: R18 with the s_sleep phase-skew REVERTED (A/B isolation: packed gates
// helped per-dispatch 82.3->79 us, but total regressed -- suspect the skew
// delayed kernel tails). Keeps: f32x2 packed gate math (v_pk_*_f32),
// direction-split (2,T,B,32) f16 buffers (no store-RFO), f16 datapath,
// fp32 acc, 16 seqs/wave, permuted gate rows (D-frag==B-frag), zero-LDS
// recurrence, exp2-folded weights, shared rcp, delayed h-stores, FC fused
// into L2 + fc_finish transpose.

#define BB 16384
#define TT 64
#define PS ((size_t)BB * 32)        // shorts per t-plane per direction
#define DS ((size_t)TT * PS)        // shorts per direction buffer
#define PT ((size_t)TT * BB * 2)    // floats per direction-partial buffer

typedef __attribute__((ext_vector_type(8))) _Float16 f16x8;
typedef __attribute__((ext_vector_type(4))) float f32x4;
typedef __attribute__((ext_vector_type(2))) float f32x2;

#if __has_builtin(__builtin_amdgcn_exp2f)
#define EXP2(x) __builtin_amdgcn_exp2f(x)
#else
#define EXP2(x) exp2f(x)
#endif
#if __has_builtin(__builtin_amdgcn_rcpf)
#define RCP(x) __builtin_amdgcn_rcpf(x)
#else
#define RCP(x) (1.0f / (x))
#endif

#define SR (-1.4426950408889634f)   // -log2(e)   for r,z gates
#define SN (-2.8853900817779268f)   // -2*log2(e) for n gate

__device__ __forceinline__ f32x2 mk2(float a, float b) {
    f32x2 v; v.x = a; v.y = b; return v;
}
__device__ __forceinline__ float tanh_fast(float x) { return 2.0f / (1.0f + __expf(-2.0f * x)) - 1.0f; }
__device__ __forceinline__ unsigned short f2h(float f) {
    _Float16 h = (_Float16)f;                      // RNE
    return __builtin_bit_cast(unsigned short, h);
}
__device__ __forceinline__ unsigned int cvt_pkh(float a, float b) {
#if __has_builtin(__builtin_amdgcn_cvt_pkrtz)
    typedef __fp16 h2_t __attribute__((ext_vector_type(2)));
    h2_t p = __builtin_amdgcn_cvt_pkrtz(a, b);
    return __builtin_bit_cast(unsigned int, p);
#else
    return (unsigned int)f2h(a) | ((unsigned int)f2h(b) << 16);
#endif
}
__device__ __forceinline__ f32x4 mfma16h(f16x8 a, f16x8 b, f32x4 c) {
    return __builtin_amdgcn_mfma_f32_16x16x32_f16(a, b, c, 0, 0, 0);
}

// Gates for a q-pair on packed f32 vectors (v_pk_* codegen).
// Inputs are exp2-prescaled preactivations (bias carried in MFMA C operand).
// sigma(x) = rcp(1+exp2(SR*x)); tanh(v) = 2*rcp(1+exp2(SN*v)) - 1.
__device__ __forceinline__ void gate_pair2(f32x2 aR, f32x2 aZ, f32x2 xN, f32x2 hN,
                                           f32x2& hp) {
    f32x2 er = mk2(EXP2(aR.x), EXP2(aR.y));
    f32x2 ez = mk2(EXP2(aZ.x), EXP2(aZ.y));
    f32x2 Ar = er + 1.f;
    f32x2 Az = ez + 1.f;
    float iR = RCP(Ar.x * Ar.y);
    float iZ = RCP(Az.x * Az.y);
    f32x2 r = mk2(iR * Ar.y, iR * Ar.x);
    f32x2 z = mk2(iZ * Az.y, iZ * Az.x);
    f32x2 v = r * hN + xN;                         // pk_fma
    f32x2 en = mk2(EXP2(v.x), EXP2(v.y));
    f32x2 An = en + 1.f;
    float iN = RCP(An.x * An.y);
    f32x2 n = mk2(fmaf(2.f, iN * An.y, -1.f), fmaf(2.f, iN * An.x, -1.f));
    hp = z * (hp - n) + n;                         // pk_sub / pk_fma
}

// A: lane = A[m=lane&15][k=(lane>>4)*8+j]   B: lane = B[k=(lane>>4)*8+j][n=lane&15]
// D: lane = D[row=(lane>>4)*4+reg][col=lane&15]
// Gate-row permutation: block row position (T*16 + qd*4 + q) <- original unit 8qd+4T+q.

template<bool IS_L0, bool IS_LAST>
__global__ __launch_bounds__(256, 2)
void gru_mfma(const float* __restrict__ x0,
              const unsigned short* __restrict__ bin,      // f16 bits (2,T,B,32)
              const float* __restrict__ Wih,               // (2,96,I)
              const float* __restrict__ Whh,               // (2,96,32)
              const float* __restrict__ bih,               // (2,96)
              const float* __restrict__ bhh,               // (2,96)
              unsigned short* __restrict__ bout,           // f16 bits (2,T,B,32)
              const float* __restrict__ Wfc,               // (2,64)  [LAST]
              float* __restrict__ pbase)                   // (2,T,B,2) fp32 [LAST]
{
    const int tid  = threadIdx.x;
    const int lane = tid & 63;
    const int wv   = tid >> 6;
    const int g    = blockIdx.x * 4 + wv;        // 0..2047
    const int d    = g >> 10;
    const int b0   = (g & 1023) * 16;            // 16 seqs per wave
    const int col  = lane & 15;
    const int qd   = lane >> 4;

    // ---- Whh A-frags (single f16), permuted rows, exp2-prescaled ----
    f16x8 whhF[6];
    {
        const float* wsrc = Whh + d * 96 * 32;
        #pragma unroll
        for (int t = 0; t < 6; ++t) {
            const float sc = (t < 4) ? SR : SN;
            const int row = (t >> 1) * 32 + 8 * (col >> 2) + 4 * (t & 1) + (col & 3);
            const float* pr = wsrc + row * 32 + qd * 8;
            unsigned short wbits[8];
            #pragma unroll
            for (int j = 0; j < 8; ++j) wbits[j] = f2h(pr[j] * sc);
            whhF[t] = __builtin_bit_cast(f16x8, *(uint4*)wbits);
        }
    }

    // ---- Wih A-frags (single f16, permuted, prescaled) or L0 scalar weights ----
    f16x8 wihF[6][2];
    float w0c[6][4], w1c[6][4];
    if constexpr (!IS_L0) {
        const float* wsrc = Wih + d * 96 * 64;
        #pragma unroll
        for (int t = 0; t < 6; ++t) {
            const float sc = (t < 4) ? SR : SN;
            const int row = (t >> 1) * 32 + 8 * (col >> 2) + 4 * (t & 1) + (col & 3);
            #pragma unroll
            for (int kc = 0; kc < 2; ++kc) {
                const float* pr = wsrc + row * 64 + kc * 32 + qd * 8;
                unsigned short wbits[8];
                #pragma unroll
                for (int j = 0; j < 8; ++j) wbits[j] = f2h(pr[j] * sc);
                wihF[t][kc] = __builtin_bit_cast(f16x8, *(uint4*)wbits);
            }
        }
    } else {
        #pragma unroll
        for (int t = 0; t < 6; ++t) {
            const float sc = (t < 4) ? SR : SN;
            #pragma unroll
            for (int q = 0; q < 4; ++q) {
                const int row = (t >> 1) * 32 + 8 * qd + 4 * (t & 1) + q;
                const float* pr = Wih + d * 96 * 2 + row * 2;
                w0c[t][q] = pr[0] * sc;
                w1c[t][q] = pr[1] * sc;
            }
        }
    }

    // ---- biases as C-operand frags (prescaled) ----
    f32x4 biasIn[6], biasHN[2];
    {
        const float* bi = bih + d * 96;
        const float* bh = bhh + d * 96;
        #pragma unroll
        for (int t = 0; t < 4; ++t) {
            const int off = (t >> 1) * 32 + 8 * qd + 4 * (t & 1);
            float4 a = *(const float4*)(bi + off);
            float4 b = *(const float4*)(bh + off);
            biasIn[t][0] = (a.x + b.x) * SR; biasIn[t][1] = (a.y + b.y) * SR;
            biasIn[t][2] = (a.z + b.z) * SR; biasIn[t][3] = (a.w + b.w) * SR;
        }
        #pragma unroll
        for (int T = 0; T < 2; ++T) {
            const int off = 64 + 8 * qd + 4 * T;
            float4 a = *(const float4*)(bi + off);
            float4 b = *(const float4*)(bh + off);
            biasIn[4 + T][0] = a.x * SN; biasIn[4 + T][1] = a.y * SN;
            biasIn[4 + T][2] = a.z * SN; biasIn[4 + T][3] = a.w * SN;
            biasHN[T][0] = b.x * SN; biasHN[T][1] = b.y * SN;
            biasHN[T][2] = b.z * SN; biasHN[T][3] = b.w * SN;
        }
    }

    // ---- FC weights per lane (LAST): unit u = 8*qd + 4*T + q ----
    float wf0[2][4], wf1[2][4];
    if constexpr (IS_LAST) {
        #pragma unroll
        for (int T = 0; T < 2; ++T)
            #pragma unroll
            for (int q = 0; q < 4; ++q) {
                const int u = 8 * qd + 4 * T + q;
                wf0[T][q] = Wfc[d * 32 + u];
                wf1[T][q] = Wfc[64 + d * 32 + u];
            }
    }

    const int t0 = d ? (TT - 1) : 0;
    const int dt = d ? -1 : 1;
    const ptrdiff_t dplane = (ptrdiff_t)dt * (ptrdiff_t)PS;   // one t-plane step

    f16x8 hF = {};
    float hprev[2][4] = {{0.f,0.f,0.f,0.f},{0.f,0.f,0.f,0.f}};

    auto REC = [&](f32x4 (&acc)[6], f32x4 (&accHN)[2]) {
        #pragma unroll
        for (int t = 0; t < 4; ++t)
            acc[t] = mfma16h(whhF[t], hF, acc[t]);
        #pragma unroll
        for (int T = 0; T < 2; ++T)
            accHN[T] = mfma16h(whhF[4 + T], hF, biasHN[T]);
    };

    auto PROJ = [&](f32x4 (&accN)[6], uint4 nx0, uint4 nx1, float2 nxs) {
        if constexpr (!IS_L0) {
            f16x8 a0 = __builtin_bit_cast(f16x8, nx0);   // k 0..31  = fwd units
            f16x8 a1 = __builtin_bit_cast(f16x8, nx1);   // k 32..63 = bwd units
            #pragma unroll
            for (int t = 0; t < 6; ++t) {
                accN[t] = mfma16h(wihF[t][0], a0, biasIn[t]);
                accN[t] = mfma16h(wihF[t][1], a1, accN[t]);
            }
        } else {
            #pragma unroll
            for (int t = 0; t < 6; ++t)
                #pragma unroll
                for (int q = 0; q < 4; ++q)
                    accN[t][q] = fmaf(nxs.x, w0c[t][q], fmaf(nxs.y, w1c[t][q], biasIn[t][q]));
        }
    };

    // ---- gates (packed f32 math); delayed h-store (L0/L1) or FC partial (LAST) ----
    auto GATES = [&](f32x4 (&acc)[6], f32x4 (&accHN)[2], unsigned short* outp,
                     uint4& hwP, unsigned short*& opP, float* poutp) {
        unsigned int hw[4];
        #pragma unroll
        for (int T = 0; T < 2; ++T) {
            f32x2 hp01 = mk2(hprev[T][0], hprev[T][1]);
            f32x2 hp23 = mk2(hprev[T][2], hprev[T][3]);
            gate_pair2(mk2(acc[T][0], acc[T][1]), mk2(acc[2 + T][0], acc[2 + T][1]),
                       mk2(acc[4 + T][0], acc[4 + T][1]), mk2(accHN[T][0], accHN[T][1]), hp01);
            gate_pair2(mk2(acc[T][2], acc[T][3]), mk2(acc[2 + T][2], acc[2 + T][3]),
                       mk2(acc[4 + T][2], acc[4 + T][3]), mk2(accHN[T][2], accHN[T][3]), hp23);
            hprev[T][0] = hp01.x; hprev[T][1] = hp01.y;
            hprev[T][2] = hp23.x; hprev[T][3] = hp23.y;
            hw[2 * T]     = cvt_pkh(hp01.x, hp01.y);
            hw[2 * T + 1] = cvt_pkh(hp23.x, hp23.y);
        }
        hF = __builtin_bit_cast(f16x8, *(uint4*)hw);
        if constexpr (IS_LAST) {
            float p0 = 0.f, p1 = 0.f;
            #pragma unroll
            for (int T = 0; T < 2; ++T)
                #pragma unroll
                for (int q = 0; q < 4; ++q) {
                    p0 = fmaf(hprev[T][q], wf0[T][q], p0);
                    p1 = fmaf(hprev[T][q], wf1[T][q], p1);
                }
            p0 += __shfl_xor(p0, 16); p0 += __shfl_xor(p0, 32);
            p1 += __shfl_xor(p1, 16); p1 += __shfl_xor(p1, 32);
            if (qd == 0) *(float2*)poutp = make_float2(p0, p1);
        } else {
            *(uint4*)opP = hwP;                 // store the 2-steps-old value
            hwP = *(uint4*)hw;                  // bank this step's value
            opP = outp;
        }
    };

    // ---- x streams: even loads x[2k+2], odd loads x[2k+3]; F/B buffer pair ----
    f32x4 accA[6], accB[6], accHN[2];
    uint4 xc0 = {}, xc1 = {}, xe0 = {}, xe1 = {};
    float2 xsc = {}, xse = {};
    const unsigned short* xFE = nullptr; const unsigned short* xBE = nullptr;
    const unsigned short* xFO = nullptr; const unsigned short* xBO = nullptr;
    const float* xfpE = nullptr; const float* xfpO = nullptr;

    if constexpr (!IS_L0) {
        const unsigned short* pF = bin + (size_t)t0 * PS + (size_t)(b0 + col) * 32 + qd * 8;
        const unsigned short* pB = pF + DS;
        uint4 a = *(const uint4*)pF, b = *(const uint4*)pB;
        PROJ(accA, a, b, {});                         // acc for step 0
        xc0 = *(const uint4*)(pF + dplane);           // x[1]
        xc1 = *(const uint4*)(pB + dplane);
        xFE = pF + 2 * dplane; xBE = pB + 2 * dplane; // x[2]
        xFO = pF + 3 * dplane; xBO = pB + 3 * dplane; // x[3]
    } else {
        const float* p0 = x0 + ((size_t)(b0 + col) * TT + t0) * 2;
        float2 xs0 = *(const float2*)p0;
        PROJ(accA, {}, {}, xs0);
        xsc = *(const float2*)(p0 + dt * 2);          // x[1]
        xfpE = p0 + dt * 4;                           // x[2]
        xfpO = p0 + dt * 6;                           // x[3]
    }

    unsigned short* optrA = nullptr; unsigned short* optrB = nullptr;
    float* poutA = nullptr; float* poutB = nullptr;
    const ptrdiff_t dpp = (ptrdiff_t)dt * (ptrdiff_t)BB * 2;
    if constexpr (IS_LAST) {
        poutA = pbase + (size_t)d * PT + ((size_t)t0 * BB + b0 + col) * 2;
        poutB = poutA + dpp;
    } else {
        optrA = bout + (size_t)d * DS + (size_t)t0 * PS + (size_t)(b0 + col) * 32 + qd * 8;
        optrB = optrA + dplane;
    }

    // delayed-store state (L0/L1): primed with zero-writes to step-0/1 addresses
    uint4 hwPrevA = {}, hwPrevB = {};
    unsigned short* opPrevA = optrA;
    unsigned short* opPrevB = optrB;

    for (int k = 0; k < 31; ++k) {                    // steps 0..61
        if constexpr (!IS_L0) {
            xe0 = *(const uint4*)xFE; xe1 = *(const uint4*)xBE;
            xFE += 2 * dplane; xBE += 2 * dplane;
        } else { xse = *(const float2*)xfpE; xfpE += dt * 4; }
        REC(accA, accHN);
        PROJ(accB, xc0, xc1, xsc);
        GATES(accA, accHN, optrA, hwPrevA, opPrevA, poutA);
        if constexpr (IS_LAST) poutA += 2 * dpp; else optrA += 2 * dplane;
        if constexpr (!IS_L0) {
            xc0 = *(const uint4*)xFO; xc1 = *(const uint4*)xBO;
            xFO += 2 * dplane; xBO += 2 * dplane;
        } else { xsc = *(const float2*)xfpO; xfpO += dt * 4; }
        REC(accB, accHN);
        PROJ(accA, xe0, xe1, xse);
        GATES(accB, accHN, optrB, hwPrevB, opPrevB, poutB);
        if constexpr (IS_LAST) poutB += 2 * dpp; else optrB += 2 * dplane;
    }
    REC(accA, accHN);                                 // step 62
    PROJ(accB, xc0, xc1, xsc);
    GATES(accA, accHN, optrA, hwPrevA, opPrevA, poutA);
    REC(accB, accHN);                                 // step 63
    GATES(accB, accHN, optrB, hwPrevB, opPrevB, poutB);
    if constexpr (!IS_LAST) {
        *(uint4*)opPrevA = hwPrevA;                   // flush banked values
        *(uint4*)opPrevB = hwPrevB;
    }
}

// out[b][t] = tanh(pf[t][b] + pb[t][b] + bfc), with an LDS 64x64 transpose
__global__ __launch_bounds__(256)
void fc_finish(const float* __restrict__ pf,    // (T,B,2)
               const float* __restrict__ pb,    // (T,B,2)
               const float* __restrict__ bfc,   // (2,)
               float* __restrict__ out)         // (B,T,2)
{
    __shared__ float2 tile[64][65];
    const int tid = threadIdx.x;
    const int bbase = blockIdx.x * 64;
    const float c0 = bfc[0], c1 = bfc[1];
    #pragma unroll
    for (int tp = 0; tp < 16; ++tp) {             // read coalesced over b
        const int t = tp * 4 + (tid >> 6);
        const int bl = tid & 63;
        const size_t idx = ((size_t)t * BB + bbase + bl) * 2;
        float2 vf = *(const float2*)(pf + idx);
        float2 vb = *(const float2*)(pb + idx);
        float2 o;
        o.x = tanh_fast(vf.x + vb.x + c0);
        o.y = tanh_fast(vf.y + vb.y + c1);
        tile[t][bl] = o;
    }
    __syncthreads();
    #pragma unroll
    for (int bp = 0; bp < 16; ++bp) {             // write coalesced over t
        const int bl = bp * 4 + (tid >> 6);
        const int t = tid & 63;
        *(float2*)(out + ((size_t)(bbase + bl) * TT + t) * 2) = tile[t][bl];
    }
}

extern "C" void kernel_launch(void* const* d_in, const int* in_sizes, int n_in,
                              void* d_out, int out_size, void* d_ws, size_t ws_size,
                              hipStream_t stream)
{
    const float* x    = (const float*)d_in[0];
    const float* Wih0 = (const float*)d_in[1];
    const float* Whh0 = (const float*)d_in[2];
    const float* bih0 = (const float*)d_in[3];
    const float* bhh0 = (const float*)d_in[4];
    const float* WihL = (const float*)d_in[5];
    const float* WhhL = (const float*)d_in[6];
    const float* bihL = (const float*)d_in[7];
    const float* bhhL = (const float*)d_in[8];
    const float* Wfc  = (const float*)d_in[9];
    const float* bfc  = (const float*)d_in[10];

    unsigned short* buf0 = (unsigned short*)d_ws;           // (2,T,B,32) f16
    unsigned short* buf1 = buf0 + 2 * DS;                   // (2,T,B,32) f16
    float* pbase = (float*)d_ws;                            // (2,T,B,2) fp32, reuses buf0
    float* out = (float*)d_out;

    gru_mfma<true, false><<<512, 256, 0, stream>>>(
        x, nullptr, Wih0, Whh0, bih0, bhh0, buf0, nullptr, nullptr);
    gru_mfma<false, false><<<512, 256, 0, stream>>>(
        nullptr, buf0, WihL, WhhL, bihL, bhhL, buf1, nullptr, nullptr);
    gru_mfma<false, true><<<512, 256, 0, stream>>>(
        nullptr, buf1, WihL + 2 * 96 * 64, WhhL + 2 * 96 * 32,
        bihL + 2 * 96, bhhL + 2 * 96, nullptr, Wfc, pbase);
    fc_finish<<<BB / 64, 256, 0, stream>>>(
        pbase, pbase + PT, bfc, out);
}